// Round 6
// baseline (76.591 us; speedup 1.0000x reference)
//
#include <hip/hip_runtime.h>
#include <math.h>

#define NEG_INF (-1e30f)

typedef __attribute__((ext_vector_type(8))) short s16x8;   // 8 bf16 = 4 VGPRs (MFMA A/B frag)
typedef __attribute__((ext_vector_type(4))) float f32x4;   // MFMA C/D frag

// RNE float->bf16 pair pack (lo -> low short, hi -> high short)
__device__ __forceinline__ unsigned int pack_bf16(float lo, float hi) {
    unsigned int ul = __float_as_uint(lo);
    ul += 0x7FFFu + ((ul >> 16) & 1u);
    unsigned int uh = __float_as_uint(hi);
    uh += 0x7FFFu + ((uh >> 16) & 1u);
    return (ul >> 16) | (uh & 0xFFFF0000u);
}

// ---- Kernel 1: one-time transpose + fp32-normalize + bf16 pack ----
// Grid 128: blocks 0-63 -> student, 64-127 -> teacher; 64 positions each.
// Output layout [n][64] bf16: one position = 128 B = 1 cache line; an MFMA
// fragment is a contiguous 16-B slice of it -> main kernel needs no LDS.
__global__ __launch_bounds__(256) void prep_kernel(
    const float* __restrict__ s, const float* __restrict__ t,
    unsigned int* __restrict__ sbf, unsigned int* __restrict__ tbf,
    float* __restrict__ accums) {
    const int b = blockIdx.x;
    const int tid = threadIdx.x;
    const int n0 = (b & 63) << 6;
    const float* __restrict__ src = (b >= 64) ? t : s;
    unsigned int* __restrict__ dst = (b >= 64) ? tbf : sbf;

    if (b == 0 && tid < 8) accums[tid] = 0.f;   // zero finalize accumulators

    __shared__ __align__(16) float lds[64][68];
    __shared__ float red[4][64];
    __shared__ float rinv[64];

    // stage fp32 [c][pos] -> LDS [pos][c]
    {
        const int cg = tid & 15;             // c-group of 4
        const int pos4 = (tid >> 4) << 2;    // 0..60
        const int base = ((n0 >> 10) << 16) + (n0 & 1023) + pos4;
#pragma unroll
        for (int cc = 0; cc < 4; ++cc) {
            const int c = (cg << 2) + cc;
            float4 v = *(const float4*)(src + base + (c << 10));
            lds[pos4 + 0][c] = v.x;
            lds[pos4 + 1][c] = v.y;
            lds[pos4 + 2][c] = v.z;
            lds[pos4 + 3][c] = v.w;
        }
    }
    __syncthreads();

    // fp32 norms (reference semantics: normalize in fp32, then round)
    {
        const int pos = tid & 63;
        const int q = tid >> 6;
        float ssq = 0.f;
#pragma unroll
        for (int j = 0; j < 4; ++j) {
            float4 v = *(const float4*)&lds[pos][(q << 4) + (j << 2)];
            ssq = fmaf(v.x, v.x, ssq);
            ssq = fmaf(v.y, v.y, ssq);
            ssq = fmaf(v.z, v.z, ssq);
            ssq = fmaf(v.w, v.w, ssq);
        }
        red[q][pos] = ssq;
    }
    __syncthreads();
    if (tid < 64) {
        float v = red[0][tid] + red[1][tid] + red[2][tid] + red[3][tid];
        rinv[tid] = 1.f / fmaxf(sqrtf(v), 1e-12f);
    }
    __syncthreads();

    // normalize, pack to bf16, write [n][64] (coalesced uint4 stores)
    {
        const int pos = tid >> 2;            // 0..63
        const int o0 = (tid & 3) << 1;       // oct pair 0,2,4,6
        const float r = rinv[pos];
        unsigned int* drow = dst + ((n0 + pos) << 5);   // 32 words/row
#pragma unroll
        for (int oo = 0; oo < 2; ++oo) {
            const int o = o0 + oo;
            const float* lp = &lds[pos][o << 3];
            uint4 u;
            u.x = pack_bf16(lp[0] * r, lp[1] * r);
            u.y = pack_bf16(lp[2] * r, lp[3] * r);
            u.z = pack_bf16(lp[4] * r, lp[5] * r);
            u.w = pack_bf16(lp[6] * r, lp[7] * r);
            *(uint4*)(drow + (o << 2)) = u;
        }
    }
}

// ---- Kernel 2: LDS-free MFMA logits + masked-softmax partials ----
// Grid 512 = 32 row-blocks(128) x 16 col-chunks(128) in-image; 2 blocks/CU.
// Fragments loaded directly from the packed [n][64] arrays:
// frag(row, quad, khalf) = uint4 at row*8 + quad + 4*khalf (16-B slices).
// Fixed-max softmax (|logit| <= ~10.3 -> exp(l-10) safe).
__global__ __launch_bounds__(256, 2) void main_kernel(
    const s16x8* __restrict__ sbf, const s16x8* __restrict__ tbf,
    const int* __restrict__ labels, float4* __restrict__ stats) {

    const int rb = blockIdx.x >> 4;
    const int jc = blockIdx.x & 15;
    const int img = rb >> 4;
    const int i0 = rb * 128;
    const int jb = img * 2048 + jc * 128;

    const int tid = threadIdx.x;
    const int lane = tid & 63;
    const int wv = tid >> 6;
    const int warow = wv << 5;           // wave handles 32 rows x 128 cols
    const int quad = lane >> 4;
    const int col16 = lane & 15;

    // A fragments: 2 row-tiles x 2 k-halves
    s16x8 afr[2][2];
#pragma unroll
    for (int rt = 0; rt < 2; ++rt) {
        const int row = i0 + warow + 16 * rt + col16;
#pragma unroll
        for (int kh = 0; kh < 2; ++kh)
            afr[rt][kh] = sbf[row * 8 + quad + 4 * kh];
    }
    // B fragments: 8 col-tiles x 2 k-halves
    s16x8 bfr[8][2];
#pragma unroll
    for (int ct = 0; ct < 8; ++ct) {
        const int col = jb + 16 * ct + col16;
#pragma unroll
        for (int kh = 0; kh < 2; ++kh)
            bfr[ct][kh] = tbf[col * 8 + quad + 4 * kh];
    }

    // labels (L1/L2-resident scalar loads)
    int labi[8], ig[8];
#pragma unroll
    for (int rt = 0; rt < 2; ++rt)
#pragma unroll
        for (int reg = 0; reg < 4; ++reg) {
            const int rr = rt * 4 + reg;
            ig[rr] = i0 + warow + 16 * rt + 4 * quad + reg;
            labi[rr] = labels[ig[rr]];
        }
    int lj[8];
#pragma unroll
    for (int ct = 0; ct < 8; ++ct) lj[ct] = labels[jb + 16 * ct + col16];

    float s_sum[8], A_sum[8], c_sum[8];
#pragma unroll
    for (int rr = 0; rr < 8; ++rr) { s_sum[rr] = 0.f; A_sum[rr] = 0.f; c_sum[rr] = 0.f; }

    // 16 tiles of 16x16: MFMA (K=64 via 2 chained) + inline epilogue.
    // C/D layout: col = lane&15, row = quad*4 + reg (verified).
#pragma unroll
    for (int ct = 0; ct < 8; ++ct) {
        const int jg = jb + 16 * ct + col16;
#pragma unroll
        for (int rt = 0; rt < 2; ++rt) {
            f32x4 z = {0.f, 0.f, 0.f, 0.f};
            z = __builtin_amdgcn_mfma_f32_16x16x32_bf16(afr[rt][0], bfr[ct][0], z, 0, 0, 0);
            z = __builtin_amdgcn_mfma_f32_16x16x32_bf16(afr[rt][1], bfr[ct][1], z, 0, 0, 0);
#pragma unroll
            for (int reg = 0; reg < 4; ++reg) {
                const int rr = rt * 4 + reg;
                float logit = z[reg] * 10.f;          // cosine / TEMPERATURE
                bool self = (jg == ig[rr]);
                float e = __expf((self ? NEG_INF : logit) - 10.f);
                s_sum[rr] += e;
                if (!self && lj[ct] == labi[rr]) { A_sum[rr] += logit; c_sum[rr] += 1.f; }
            }
        }
    }

    // reduce across the 16 col lanes (low 4 lane bits)
#pragma unroll
    for (int off = 1; off < 16; off <<= 1)
#pragma unroll
        for (int rr = 0; rr < 8; ++rr) {
            s_sum[rr] += __shfl_xor(s_sum[rr], off, 64);
            A_sum[rr] += __shfl_xor(A_sum[rr], off, 64);
            c_sum[rr] += __shfl_xor(c_sum[rr], off, 64);
        }

    if (col16 == 0) {
#pragma unroll
        for (int rr = 0; rr < 8; ++rr)
            stats[ig[rr] * 16 + jc] = make_float4(s_sum[rr], A_sum[rr], c_sum[rr], 0.f);
    }
}

// ---- Kernel 3: sum 16 chunk partials per row, atomic global reduce ----
// lse = 10 + log(sum exp(l-10)). 16 blocks = 48 far-atomics (proven cheap).
__global__ __launch_bounds__(256) void finalize_kernel(
    const float4* __restrict__ stats, const int* __restrict__ labels,
    float* __restrict__ accums, float* __restrict__ out) {
    const int tid = threadIdx.x;
    const int r = blockIdx.x * 256 + tid;

    float ssum = 0.f, A = 0.f, cnt = 0.f;
#pragma unroll
    for (int c = 0; c < 16; ++c) {
        float4 v = stats[r * 16 + c];
        ssum += v.x; A += v.y; cnt += v.z;
    }
    float mlpp = 0.f, val = 0.f, nbv = 0.f;
    if (cnt > 0.5f) {   // integer count; > EPS <=> >= 1
        float lse = 10.f + __logf(ssum);
        mlpp = (A - cnt * lse) / (cnt + 1e-8f);
        val = 1.f;
        nbv = (labels[r] != 0) ? 1.f : 0.f;
    }

    __shared__ float red0[256], red1[256], red2[256];
    red0[tid] = mlpp; red1[tid] = val; red2[tid] = nbv;
    __syncthreads();
    for (int off = 128; off > 0; off >>= 1) {
        if (tid < off) {
            red0[tid] += red0[tid + off];
            red1[tid] += red1[tid + off];
            red2[tid] += red2[tid + off];
        }
        __syncthreads();
    }

    if (tid == 0) {
        atomicAdd(&accums[0], red0[0]);
        atomicAdd(&accums[1], red1[0]);
        atomicAdd(&accums[2], red2[0]);
        __threadfence();
        unsigned int old = atomicAdd((unsigned int*)&accums[3], 1u);
        if (old == 15u) {
            float S = atomicAdd(&accums[0], 0.f);
            float V = atomicAdd(&accums[1], 0.f);
            float NB = atomicAdd(&accums[2], 0.f);
            float loss = -S / V;
            out[0] = loss * NB / (NB + 1e-8f);
        }
    }
}

extern "C" void kernel_launch(void* const* d_in, const int* in_sizes, int n_in,
                              void* d_out, int out_size, void* d_ws, size_t ws_size,
                              hipStream_t stream) {
    const float* s = (const float*)d_in[0];
    const float* t = (const float*)d_in[1];
    const int* labels = (const int*)d_in[2];
    float* out = (float*)d_out;

    char* ws = (char*)d_ws;
    float* accums = (float*)ws;                          // 32 B
    unsigned int* sbf = (unsigned int*)(ws + 1024);      // 4096*128 B = 512 KB
    unsigned int* tbf = (unsigned int*)(ws + 1024 + 524288);
    float4* stats = (float4*)(ws + 1024 + 2 * 524288);   // 4096*16*16 B = 1 MB

    hipLaunchKernelGGL(prep_kernel, dim3(128), dim3(256), 0, stream,
                       s, t, sbf, tbf, accums);
    hipLaunchKernelGGL(main_kernel, dim3(512), dim3(256), 0, stream,
                       (const s16x8*)sbf, (const s16x8*)tbf, labels, stats);
    hipLaunchKernelGGL(finalize_kernel, dim3(16), dim3(256), 0, stream,
                       stats, labels, accums, out);
}